// Round 2
// baseline (212.999 us; speedup 1.0000x reference)
//
#include <hip/hip_runtime.h>
#include <math.h>

#define BS 256
#define NB 2048
#define NWAVES (BS / 64)

// ---------- wave reduction helpers ----------
__device__ inline double wred_sum(double v) {
#pragma unroll
    for (int o = 32; o > 0; o >>= 1) v += __shfl_down(v, o, 64);
    return v;
}
__device__ inline float wred_min(float v) {
#pragma unroll
    for (int o = 32; o > 0; o >>= 1) v = fminf(v, __shfl_down(v, o, 64));
    return v;
}
__device__ inline float wred_max(float v) {
#pragma unroll
    for (int o = 32; o > 0; o >>= 1) v = fmaxf(v, __shfl_down(v, o, 64));
    return v;
}

// ---------- kernel 1: stats over targets + last-block finalize ----------
__global__ void __launch_bounds__(BS) k_stats(
        const float* __restrict__ t, int n,
        double* __restrict__ bsum, double* __restrict__ bss,
        float* __restrict__ bmn, float* __restrict__ bmx,
        unsigned* __restrict__ cnt, float* __restrict__ stats) {
    int tid = blockIdx.x * BS + threadIdx.x;
    int stride = gridDim.x * BS;
    int n4 = n >> 2;
    const float4* t4 = (const float4*)t;

    double s = 0.0, ss = 0.0;
    float mn = 3.4e38f, mx = -3.4e38f;
    for (int i = tid; i < n4; i += stride) {
        float4 v = t4[i];
        mn = fminf(mn, fminf(fminf(v.x, v.y), fminf(v.z, v.w)));
        mx = fmaxf(mx, fmaxf(fmaxf(v.x, v.y), fmaxf(v.z, v.w)));
        s += (double)v.x + (double)v.y + (double)v.z + (double)v.w;
        ss += (double)v.x * v.x + (double)v.y * v.y
            + (double)v.z * v.z + (double)v.w * v.w;
    }
    if (tid == 0) {  // scalar tail (n % 4), robustness only
        for (int i = (n4 << 2); i < n; i++) {
            float v = t[i];
            mn = fminf(mn, v); mx = fmaxf(mx, v);
            s += v; ss += (double)v * v;
        }
    }

    s = wred_sum(s); ss = wred_sum(ss); mn = wred_min(mn); mx = wred_max(mx);

    __shared__ double sh_s[NWAVES], sh_ss[NWAVES];
    __shared__ float sh_mn[NWAVES], sh_mx[NWAVES];
    __shared__ unsigned s_islast;
    int wid = threadIdx.x >> 6, lane = threadIdx.x & 63;
    if (lane == 0) { sh_s[wid] = s; sh_ss[wid] = ss; sh_mn[wid] = mn; sh_mx[wid] = mx; }
    __syncthreads();
    if (threadIdx.x == 0) {
        double S = sh_s[0], SS = sh_ss[0];
        float MN = sh_mn[0], MX = sh_mx[0];
        for (int i = 1; i < NWAVES; i++) {
            S += sh_s[i]; SS += sh_ss[i];
            MN = fminf(MN, sh_mn[i]); MX = fmaxf(MX, sh_mx[i]);
        }
        bsum[blockIdx.x] = S; bss[blockIdx.x] = SS;
        bmn[blockIdx.x] = MN; bmx[blockIdx.x] = MX;
        __threadfence();  // release partials (device scope)
        unsigned prev = __hip_atomic_fetch_add(cnt, 1u, __ATOMIC_ACQ_REL,
                                               __HIP_MEMORY_SCOPE_AGENT);
        s_islast = (prev == (unsigned)(gridDim.x - 1)) ? 1u : 0u;
    }
    __syncthreads();
    if (!s_islast) return;

    // ---- last block: fold all partials (fixed order -> deterministic) ----
    __threadfence();  // acquire side
    double fs = 0.0, fss = 0.0;
    float fmn = 3.4e38f, fmx = -3.4e38f;
    for (int i = threadIdx.x; i < gridDim.x; i += BS) {
        fs += bsum[i]; fss += bss[i];
        fmn = fminf(fmn, bmn[i]); fmx = fmaxf(fmx, bmx[i]);
    }
    fs = wred_sum(fs); fss = wred_sum(fss); fmn = wred_min(fmn); fmx = wred_max(fmx);
    __syncthreads();  // reuse shared arrays safely
    if (lane == 0) { sh_s[wid] = fs; sh_ss[wid] = fss; sh_mn[wid] = fmn; sh_mx[wid] = fmx; }
    __syncthreads();
    if (threadIdx.x == 0) {
        double S = sh_s[0], SS = sh_ss[0];
        float MN = sh_mn[0], MX = sh_mx[0];
        for (int i = 1; i < NWAVES; i++) {
            S += sh_s[i]; SS += sh_ss[i];
            MN = fminf(MN, sh_mn[i]); MX = fmaxf(MX, sh_mx[i]);
        }
        double dn = (double)n;
        double mean = S / dn;
        double var = (SS - S * S / dn) / (dn - 1.0);   // ddof=1
        double sd = sqrt(var);
        float gmin = MN, gmax = MX;
        float m1 = (float)(mean + sd);
        float m2 = (float)(mean + 3.0 * sd);
        stats[0] = gmin;
        stats[1] = m1;
        stats[2] = m2;
        stats[3] = gmax;
        stats[4] = 0.2f / (m1 - gmin);   // low slope
        stats[5] = 0.5f / (m2 - m1);     // mid slope
        stats[6] = 0.3f / (gmax - m2);   // high slope
    }
}

// ---------- kernel 2: weighted L1 + last-block final mean ----------
__device__ inline float welem(float g, float x, float gmin, float m1, float m2,
                              float sl, float sm, float shv) {
    float w = (g <= m1) ? (g - gmin) * sl
            : (g <= m2) ? (g - m1) * sm + 0.2f
                        : (g - m2) * shv + 0.7f;
    return fabsf(g - x) * w;
}

__global__ void __launch_bounds__(BS) k_loss(
        const float* __restrict__ x, const float* __restrict__ t, int n,
        const float* __restrict__ stats, double* __restrict__ bsum,
        unsigned* __restrict__ cnt, float* __restrict__ out) {
    float gmin = stats[0], m1 = stats[1], m2 = stats[2];
    float sl = stats[4], sm = stats[5], shv = stats[6];
    int tid = blockIdx.x * BS + threadIdx.x;
    int stride = gridDim.x * BS;
    int n4 = n >> 2;
    const float4* x4 = (const float4*)x;
    const float4* t4 = (const float4*)t;

    double acc = 0.0;
    for (int i = tid; i < n4; i += stride) {
        float4 tv = t4[i], xv = x4[i];
        float e0 = welem(tv.x, xv.x, gmin, m1, m2, sl, sm, shv);
        float e1 = welem(tv.y, xv.y, gmin, m1, m2, sl, sm, shv);
        float e2 = welem(tv.z, xv.z, gmin, m1, m2, sl, sm, shv);
        float e3 = welem(tv.w, xv.w, gmin, m1, m2, sl, sm, shv);
        acc += (double)e0 + (double)e1 + (double)e2 + (double)e3;
    }
    if (tid == 0) {  // scalar tail
        for (int i = (n4 << 2); i < n; i++)
            acc += (double)welem(t[i], x[i], gmin, m1, m2, sl, sm, shv);
    }

    acc = wred_sum(acc);
    __shared__ double sh_s[NWAVES];
    __shared__ unsigned s_islast;
    int wid = threadIdx.x >> 6, lane = threadIdx.x & 63;
    if (lane == 0) sh_s[wid] = acc;
    __syncthreads();
    if (threadIdx.x == 0) {
        double S = sh_s[0];
        for (int i = 1; i < NWAVES; i++) S += sh_s[i];
        bsum[blockIdx.x] = S;
        __threadfence();
        unsigned prev = __hip_atomic_fetch_add(cnt, 1u, __ATOMIC_ACQ_REL,
                                               __HIP_MEMORY_SCOPE_AGENT);
        s_islast = (prev == (unsigned)(gridDim.x - 1)) ? 1u : 0u;
    }
    __syncthreads();
    if (!s_islast) return;

    __threadfence();
    double fs = 0.0;
    for (int i = threadIdx.x; i < gridDim.x; i += BS) fs += bsum[i];
    fs = wred_sum(fs);
    __syncthreads();
    if (lane == 0) sh_s[wid] = fs;
    __syncthreads();
    if (threadIdx.x == 0) {
        double S = sh_s[0];
        for (int i = 1; i < NWAVES; i++) S += sh_s[i];
        out[0] = (float)(S / (double)n);
    }
}

extern "C" void kernel_launch(void* const* d_in, const int* in_sizes, int n_in,
                              void* d_out, int out_size, void* d_ws, size_t ws_size,
                              hipStream_t stream) {
    const float* inp = (const float*)d_in[0];
    const float* tgt = (const float*)d_in[1];
    int n = in_sizes[0];

    // workspace layout (bytes):
    //   [0, 8)                      two u32 arrival counters
    //   [256,       256+16384)      double sum1[NB]
    //   [+16384,    +32768)         double ss1[NB]
    //   [+32768,    +40960)         float  mn1[NB]
    //   [+40960,    +49152)         float  mx1[NB]
    //   [+49152,    +49216)         float  stats[16]
    //   [+49280,    +65664)         double sum2[NB]
    char* ws = (char*)d_ws;
    unsigned* cnt0 = (unsigned*)ws;
    unsigned* cnt1 = (unsigned*)(ws + 4);
    char* base = ws + 256;
    double* sum1  = (double*)(base);
    double* ss1   = (double*)(base + 16384);
    float*  mn1   = (float*)(base + 32768);
    float*  mx1   = (float*)(base + 40960);
    float*  stats = (float*)(base + 49152);
    double* sum2  = (double*)(base + 49280);

    // zero the arrival counters every call (graph-capturable, deterministic)
    hipMemsetAsync(ws, 0, 8, stream);

    k_stats<<<NB, BS, 0, stream>>>(tgt, n, sum1, ss1, mn1, mx1, cnt0, stats);
    k_loss<<<NB, BS, 0, stream>>>(inp, tgt, n, stats, sum2, cnt1, (float*)d_out);
}

// Round 3
// 202.423 us; speedup vs baseline: 1.0522x; 1.0522x over previous
//
#include <hip/hip_runtime.h>
#include <math.h>

#define BS 256
#define NB 2048
#define NWAVES (BS / 64)
#define FXS 4294967296.0   // 2^32 fixed-point scale (deterministic integer join)

// ---------- wave reduction helpers ----------
__device__ inline double wred_sum(double v) {
#pragma unroll
    for (int o = 32; o > 0; o >>= 1) v += __shfl_down(v, o, 64);
    return v;
}
__device__ inline float wred_min(float v) {
#pragma unroll
    for (int o = 32; o > 0; o >>= 1) v = fminf(v, __shfl_down(v, o, 64));
    return v;
}
__device__ inline float wred_max(float v) {
#pragma unroll
    for (int o = 32; o > 0; o >>= 1) v = fmaxf(v, __shfl_down(v, o, 64));
    return v;
}

// order-preserving float -> u32 key (monotone increasing)
__device__ inline unsigned fkey(float f) {
    unsigned u = __float_as_uint(f);
    return (u & 0x80000000u) ? ~u : (u | 0x80000000u);
}
__device__ inline float funkey(unsigned k) {
    unsigned u = (k & 0x80000000u) ? (k & 0x7FFFFFFFu) : ~k;
    return __uint_as_float(u);
}

// accumulator block layout (in d_ws, zeroed by one memset each call):
//   [0]  unsigned cnt0          [4]  unsigned cnt1
//   [8]  long long sum_fx       [16] long long ss_fx
//   [24] long long loss_fx
//   [32] unsigned maxk  (max of fkey(g), init 0 ok: keys of real data > 0)
//   [36] unsigned minc  (max of ~fkey(g) -> min via complement, init 0 ok)
// stats (plain stores, visible to next kernel via dispatch-boundary release):
//   ws+128: float stats[8] = {gmin, m1, m2, gmax, sl, sm, sh}

// ---------- kernel 1: stats over targets, fence-free atomic join ----------
__global__ void __launch_bounds__(BS) k_stats(
        const float* __restrict__ t, int n,
        unsigned* __restrict__ cnt,
        long long* __restrict__ sum_fx, long long* __restrict__ ss_fx,
        unsigned* __restrict__ maxk, unsigned* __restrict__ minc,
        float* __restrict__ stats) {
    int tid = blockIdx.x * BS + threadIdx.x;
    const int stride = NB * BS;
    int n4 = n >> 2;
    const float4* t4 = (const float4*)t;

    double s = 0.0, ss = 0.0;
    float mn = 3.4e38f, mx = -3.4e38f;
    int i = tid;
    for (; i + stride < n4; i += 2 * stride) {      // ILP x2
        float4 a = t4[i];
        float4 b = t4[i + stride];
        mn = fminf(mn, fminf(fminf(a.x, a.y), fminf(a.z, a.w)));
        mx = fmaxf(mx, fmaxf(fmaxf(a.x, a.y), fmaxf(a.z, a.w)));
        s += (double)a.x + (double)a.y + (double)a.z + (double)a.w;
        ss += (double)a.x * a.x + (double)a.y * a.y
            + (double)a.z * a.z + (double)a.w * a.w;
        mn = fminf(mn, fminf(fminf(b.x, b.y), fminf(b.z, b.w)));
        mx = fmaxf(mx, fmaxf(fmaxf(b.x, b.y), fmaxf(b.z, b.w)));
        s += (double)b.x + (double)b.y + (double)b.z + (double)b.w;
        ss += (double)b.x * b.x + (double)b.y * b.y
            + (double)b.z * b.z + (double)b.w * b.w;
    }
    for (; i < n4; i += stride) {
        float4 a = t4[i];
        mn = fminf(mn, fminf(fminf(a.x, a.y), fminf(a.z, a.w)));
        mx = fmaxf(mx, fmaxf(fmaxf(a.x, a.y), fmaxf(a.z, a.w)));
        s += (double)a.x + (double)a.y + (double)a.z + (double)a.w;
        ss += (double)a.x * a.x + (double)a.y * a.y
            + (double)a.z * a.z + (double)a.w * a.w;
    }
    if (tid == 0) {  // scalar tail (n % 4), robustness only
        for (int j = (n4 << 2); j < n; j++) {
            float v = t[j];
            mn = fminf(mn, v); mx = fmaxf(mx, v);
            s += v; ss += (double)v * v;
        }
    }

    s = wred_sum(s); ss = wred_sum(ss); mn = wred_min(mn); mx = wred_max(mx);

    __shared__ double sh_s[NWAVES], sh_ss[NWAVES];
    __shared__ float sh_mn[NWAVES], sh_mx[NWAVES];
    __shared__ unsigned s_islast;
    int wid = threadIdx.x >> 6, lane = threadIdx.x & 63;
    if (lane == 0) { sh_s[wid] = s; sh_ss[wid] = ss; sh_mn[wid] = mn; sh_mx[wid] = mx; }
    __syncthreads();
    if (threadIdx.x == 0) {
        double S = sh_s[0], SS = sh_ss[0];
        float MN = sh_mn[0], MX = sh_mx[0];
        for (int k = 1; k < NWAVES; k++) {
            S += sh_s[k]; SS += sh_ss[k];
            MN = fminf(MN, sh_mn[k]); MX = fmaxf(MX, sh_mx[k]);
        }
        // fence-free join: values travel THROUGH relaxed device-scope atomics
        __hip_atomic_fetch_add(sum_fx, (long long)llrint(S * FXS),
                               __ATOMIC_RELAXED, __HIP_MEMORY_SCOPE_AGENT);
        __hip_atomic_fetch_add(ss_fx, (long long)llrint(SS * FXS),
                               __ATOMIC_RELAXED, __HIP_MEMORY_SCOPE_AGENT);
        __hip_atomic_fetch_max(maxk, fkey(MX),
                               __ATOMIC_RELAXED, __HIP_MEMORY_SCOPE_AGENT);
        __hip_atomic_fetch_max(minc, ~fkey(MN),
                               __ATOMIC_RELAXED, __HIP_MEMORY_SCOPE_AGENT);
        // wait for completion acks (NO cache maintenance), then arrive
        asm volatile("s_waitcnt vmcnt(0)" ::: "memory");
        unsigned prev = __hip_atomic_fetch_add(cnt, 1u, __ATOMIC_RELAXED,
                                               __HIP_MEMORY_SCOPE_AGENT);
        s_islast = (prev == (unsigned)(NB - 1)) ? 1u : 0u;
    }
    __syncthreads();
    if (!s_islast) return;

    if (threadIdx.x == 0) {
        asm volatile("" ::: "memory");
        long long Sfx  = __hip_atomic_load(sum_fx, __ATOMIC_RELAXED, __HIP_MEMORY_SCOPE_AGENT);
        long long SSfx = __hip_atomic_load(ss_fx,  __ATOMIC_RELAXED, __HIP_MEMORY_SCOPE_AGENT);
        unsigned  MK   = __hip_atomic_load(maxk,   __ATOMIC_RELAXED, __HIP_MEMORY_SCOPE_AGENT);
        unsigned  MC   = __hip_atomic_load(minc,   __ATOMIC_RELAXED, __HIP_MEMORY_SCOPE_AGENT);
        double S  = (double)Sfx  / FXS;
        double SS = (double)SSfx / FXS;
        float gmax = funkey(MK);
        float gmin = funkey(~MC);
        double dn = (double)n;
        double mean = S / dn;
        double var = (SS - S * S / dn) / (dn - 1.0);   // ddof=1
        double sd = sqrt(var);
        float m1 = (float)(mean + sd);
        float m2 = (float)(mean + 3.0 * sd);
        stats[0] = gmin;
        stats[1] = m1;
        stats[2] = m2;
        stats[3] = gmax;
        stats[4] = 0.2f / (m1 - gmin);   // low slope
        stats[5] = 0.5f / (m2 - m1);     // mid slope
        stats[6] = 0.3f / (gmax - m2);   // high slope
    }
}

// ---------- kernel 2: weighted L1, fence-free atomic join ----------
__device__ inline float welem(float g, float x, float gmin, float m1, float m2,
                              float sl, float sm, float shv) {
    float w = (g <= m1) ? (g - gmin) * sl
            : (g <= m2) ? (g - m1) * sm + 0.2f
                        : (g - m2) * shv + 0.7f;
    return fabsf(g - x) * w;
}

__global__ void __launch_bounds__(BS) k_loss(
        const float* __restrict__ x, const float* __restrict__ t, int n,
        const float* __restrict__ stats,
        unsigned* __restrict__ cnt, long long* __restrict__ loss_fx,
        float* __restrict__ out) {
    float gmin = stats[0], m1 = stats[1], m2 = stats[2];
    float sl = stats[4], sm = stats[5], shv = stats[6];
    int tid = blockIdx.x * BS + threadIdx.x;
    const int stride = NB * BS;
    int n4 = n >> 2;
    const float4* x4 = (const float4*)x;
    const float4* t4 = (const float4*)t;

    double acc = 0.0;
    int i = tid;
    for (; i + stride < n4; i += 2 * stride) {      // ILP x2
        float4 tv = t4[i], xv = x4[i];
        float4 tw = t4[i + stride], xw = x4[i + stride];
        float e0 = welem(tv.x, xv.x, gmin, m1, m2, sl, sm, shv);
        float e1 = welem(tv.y, xv.y, gmin, m1, m2, sl, sm, shv);
        float e2 = welem(tv.z, xv.z, gmin, m1, m2, sl, sm, shv);
        float e3 = welem(tv.w, xv.w, gmin, m1, m2, sl, sm, shv);
        acc += (double)e0 + (double)e1 + (double)e2 + (double)e3;
        float f0 = welem(tw.x, xw.x, gmin, m1, m2, sl, sm, shv);
        float f1 = welem(tw.y, xw.y, gmin, m1, m2, sl, sm, shv);
        float f2 = welem(tw.z, xw.z, gmin, m1, m2, sl, sm, shv);
        float f3 = welem(tw.w, xw.w, gmin, m1, m2, sl, sm, shv);
        acc += (double)f0 + (double)f1 + (double)f2 + (double)f3;
    }
    for (; i < n4; i += stride) {
        float4 tv = t4[i], xv = x4[i];
        float e0 = welem(tv.x, xv.x, gmin, m1, m2, sl, sm, shv);
        float e1 = welem(tv.y, xv.y, gmin, m1, m2, sl, sm, shv);
        float e2 = welem(tv.z, xv.z, gmin, m1, m2, sl, sm, shv);
        float e3 = welem(tv.w, xv.w, gmin, m1, m2, sl, sm, shv);
        acc += (double)e0 + (double)e1 + (double)e2 + (double)e3;
    }
    if (tid == 0) {  // scalar tail
        for (int j = (n4 << 2); j < n; j++)
            acc += (double)welem(t[j], x[j], gmin, m1, m2, sl, sm, shv);
    }

    acc = wred_sum(acc);
    __shared__ double sh_s[NWAVES];
    __shared__ unsigned s_islast;
    int wid = threadIdx.x >> 6, lane = threadIdx.x & 63;
    if (lane == 0) sh_s[wid] = acc;
    __syncthreads();
    if (threadIdx.x == 0) {
        double S = sh_s[0];
        for (int k = 1; k < NWAVES; k++) S += sh_s[k];
        __hip_atomic_fetch_add(loss_fx, (long long)llrint(S * FXS),
                               __ATOMIC_RELAXED, __HIP_MEMORY_SCOPE_AGENT);
        asm volatile("s_waitcnt vmcnt(0)" ::: "memory");
        unsigned prev = __hip_atomic_fetch_add(cnt, 1u, __ATOMIC_RELAXED,
                                               __HIP_MEMORY_SCOPE_AGENT);
        s_islast = (prev == (unsigned)(NB - 1)) ? 1u : 0u;
    }
    __syncthreads();
    if (!s_islast) return;

    if (threadIdx.x == 0) {
        asm volatile("" ::: "memory");
        long long L = __hip_atomic_load(loss_fx, __ATOMIC_RELAXED, __HIP_MEMORY_SCOPE_AGENT);
        out[0] = (float)(((double)L / FXS) / (double)n);
    }
}

extern "C" void kernel_launch(void* const* d_in, const int* in_sizes, int n_in,
                              void* d_out, int out_size, void* d_ws, size_t ws_size,
                              hipStream_t stream) {
    const float* inp = (const float*)d_in[0];
    const float* tgt = (const float*)d_in[1];
    int n = in_sizes[0];

    char* ws = (char*)d_ws;
    unsigned*  cnt0    = (unsigned*)(ws + 0);
    unsigned*  cnt1    = (unsigned*)(ws + 4);
    long long* sum_fx  = (long long*)(ws + 8);
    long long* ss_fx   = (long long*)(ws + 16);
    long long* loss_fx = (long long*)(ws + 24);
    unsigned*  maxk    = (unsigned*)(ws + 32);
    unsigned*  minc    = (unsigned*)(ws + 36);
    float*     stats   = (float*)(ws + 128);

    // one small memset zeroes counters + all integer accumulators each call
    hipMemsetAsync(ws, 0, 64, stream);

    k_stats<<<NB, BS, 0, stream>>>(tgt, n, cnt0, sum_fx, ss_fx, maxk, minc, stats);
    k_loss<<<NB, BS, 0, stream>>>(inp, tgt, n, stats, cnt1, loss_fx, (float*)d_out);
}

// Round 4
// 46.357 us; speedup vs baseline: 4.5947x; 4.3666x over previous
//
#include <hip/hip_runtime.h>
#include <math.h>

#define BS 256          // big-kernel block size
#define NB 2048         // big-kernel grid
#define NWAVES (BS / 64)
#define TBS 1024        // fold-kernel block size
#define TNW (TBS / 64)

// ---------- wave reduction helpers ----------
__device__ inline double wred_sum(double v) {
#pragma unroll
    for (int o = 32; o > 0; o >>= 1) v += __shfl_down(v, o, 64);
    return v;
}
__device__ inline float wred_min(float v) {
#pragma unroll
    for (int o = 32; o > 0; o >>= 1) v = fminf(v, __shfl_down(v, o, 64));
    return v;
}
__device__ inline float wred_max(float v) {
#pragma unroll
    for (int o = 32; o > 0; o >>= 1) v = fmaxf(v, __shfl_down(v, o, 64));
    return v;
}

// ---------- pass 1: per-block {sum, sumsq, min, max} over targets ----------
// Plain scattered stores; coherence comes from the dispatch boundary.
__global__ void __launch_bounds__(BS) k_stats(
        const float* __restrict__ t, int n,
        double* __restrict__ bsum, double* __restrict__ bss,
        float* __restrict__ bmn, float* __restrict__ bmx) {
    int tid = blockIdx.x * BS + threadIdx.x;
    const int stride = NB * BS;
    int n4 = n >> 2;
    const float4* t4 = (const float4*)t;

    double s = 0.0, ss = 0.0;
    float mn = 3.4e38f, mx = -3.4e38f;
    int i = tid;
    for (; i + stride < n4; i += 2 * stride) {      // ILP x2: two independent streams
        float4 a = t4[i];
        float4 b = t4[i + stride];
        mn = fminf(mn, fminf(fminf(a.x, a.y), fminf(a.z, a.w)));
        mx = fmaxf(mx, fmaxf(fmaxf(a.x, a.y), fmaxf(a.z, a.w)));
        s += (double)a.x + (double)a.y + (double)a.z + (double)a.w;
        ss += (double)a.x * a.x + (double)a.y * a.y
            + (double)a.z * a.z + (double)a.w * a.w;
        mn = fminf(mn, fminf(fminf(b.x, b.y), fminf(b.z, b.w)));
        mx = fmaxf(mx, fmaxf(fmaxf(b.x, b.y), fmaxf(b.z, b.w)));
        s += (double)b.x + (double)b.y + (double)b.z + (double)b.w;
        ss += (double)b.x * b.x + (double)b.y * b.y
            + (double)b.z * b.z + (double)b.w * b.w;
    }
    for (; i < n4; i += stride) {
        float4 a = t4[i];
        mn = fminf(mn, fminf(fminf(a.x, a.y), fminf(a.z, a.w)));
        mx = fmaxf(mx, fmaxf(fmaxf(a.x, a.y), fmaxf(a.z, a.w)));
        s += (double)a.x + (double)a.y + (double)a.z + (double)a.w;
        ss += (double)a.x * a.x + (double)a.y * a.y
            + (double)a.z * a.z + (double)a.w * a.w;
    }
    if (tid == 0) {  // scalar tail (n % 4), robustness only
        for (int j = (n4 << 2); j < n; j++) {
            float v = t[j];
            mn = fminf(mn, v); mx = fmaxf(mx, v);
            s += v; ss += (double)v * v;
        }
    }

    s = wred_sum(s); ss = wred_sum(ss); mn = wred_min(mn); mx = wred_max(mx);

    __shared__ double sh_s[NWAVES], sh_ss[NWAVES];
    __shared__ float sh_mn[NWAVES], sh_mx[NWAVES];
    int wid = threadIdx.x >> 6, lane = threadIdx.x & 63;
    if (lane == 0) { sh_s[wid] = s; sh_ss[wid] = ss; sh_mn[wid] = mn; sh_mx[wid] = mx; }
    __syncthreads();
    if (threadIdx.x == 0) {
        double S = sh_s[0], SS = sh_ss[0];
        float MN = sh_mn[0], MX = sh_mx[0];
        for (int k = 1; k < NWAVES; k++) {
            S += sh_s[k]; SS += sh_ss[k];
            MN = fminf(MN, sh_mn[k]); MX = fmaxf(MX, sh_mx[k]);
        }
        bsum[blockIdx.x] = S; bss[blockIdx.x] = SS;
        bmn[blockIdx.x] = MN; bmx[blockIdx.x] = MX;
    }
}

// ---------- pass 2: fold block partials -> piecewise-weight constants ----------
__global__ void __launch_bounds__(TBS) k_finalize_stats(
        const double* __restrict__ bsum, const double* __restrict__ bss,
        const float* __restrict__ bmn, const float* __restrict__ bmx,
        long long n, float* __restrict__ stats) {
    double s = 0.0, ss = 0.0;
    float mn = 3.4e38f, mx = -3.4e38f;
    for (int i = threadIdx.x; i < NB; i += TBS) {
        s += bsum[i]; ss += bss[i];
        mn = fminf(mn, bmn[i]); mx = fmaxf(mx, bmx[i]);
    }
    s = wred_sum(s); ss = wred_sum(ss); mn = wred_min(mn); mx = wred_max(mx);

    __shared__ double sh_s[TNW], sh_ss[TNW];
    __shared__ float sh_mn[TNW], sh_mx[TNW];
    int wid = threadIdx.x >> 6, lane = threadIdx.x & 63;
    if (lane == 0) { sh_s[wid] = s; sh_ss[wid] = ss; sh_mn[wid] = mn; sh_mx[wid] = mx; }
    __syncthreads();
    if (threadIdx.x == 0) {
        double S = sh_s[0], SS = sh_ss[0];
        float MN = sh_mn[0], MX = sh_mx[0];
        for (int i = 1; i < TNW; i++) {
            S += sh_s[i]; SS += sh_ss[i];
            MN = fminf(MN, sh_mn[i]); MX = fmaxf(MX, sh_mx[i]);
        }
        double dn = (double)n;
        double mean = S / dn;
        double var = (SS - S * S / dn) / (dn - 1.0);   // ddof=1
        double sd = sqrt(var);
        float gmin = MN, gmax = MX;
        float m1 = (float)(mean + sd);
        float m2 = (float)(mean + 3.0 * sd);
        stats[0] = gmin;
        stats[1] = m1;
        stats[2] = m2;
        stats[3] = gmax;
        stats[4] = 0.2f / (m1 - gmin);   // low slope
        stats[5] = 0.5f / (m2 - m1);     // mid slope
        stats[6] = 0.3f / (gmax - m2);   // high slope
    }
}

// ---------- pass 3: weighted L1 partial sums ----------
__device__ inline float welem(float g, float x, float gmin, float m1, float m2,
                              float sl, float sm, float shv) {
    float w = (g <= m1) ? (g - gmin) * sl
            : (g <= m2) ? (g - m1) * sm + 0.2f
                        : (g - m2) * shv + 0.7f;
    return fabsf(g - x) * w;
}

__global__ void __launch_bounds__(BS) k_loss(
        const float* __restrict__ x, const float* __restrict__ t, int n,
        const float* __restrict__ stats, double* __restrict__ bsum) {
    float gmin = stats[0], m1 = stats[1], m2 = stats[2];
    float sl = stats[4], sm = stats[5], shv = stats[6];
    int tid = blockIdx.x * BS + threadIdx.x;
    const int stride = NB * BS;
    int n4 = n >> 2;
    const float4* x4 = (const float4*)x;
    const float4* t4 = (const float4*)t;

    double acc = 0.0;
    int i = tid;
    for (; i + stride < n4; i += 2 * stride) {      // ILP x2
        float4 tv = t4[i], xv = x4[i];
        float4 tw = t4[i + stride], xw = x4[i + stride];
        float e0 = welem(tv.x, xv.x, gmin, m1, m2, sl, sm, shv);
        float e1 = welem(tv.y, xv.y, gmin, m1, m2, sl, sm, shv);
        float e2 = welem(tv.z, xv.z, gmin, m1, m2, sl, sm, shv);
        float e3 = welem(tv.w, xv.w, gmin, m1, m2, sl, sm, shv);
        acc += (double)e0 + (double)e1 + (double)e2 + (double)e3;
        float f0 = welem(tw.x, xw.x, gmin, m1, m2, sl, sm, shv);
        float f1 = welem(tw.y, xw.y, gmin, m1, m2, sl, sm, shv);
        float f2 = welem(tw.z, xw.z, gmin, m1, m2, sl, sm, shv);
        float f3 = welem(tw.w, xw.w, gmin, m1, m2, sl, sm, shv);
        acc += (double)f0 + (double)f1 + (double)f2 + (double)f3;
    }
    for (; i < n4; i += stride) {
        float4 tv = t4[i], xv = x4[i];
        float e0 = welem(tv.x, xv.x, gmin, m1, m2, sl, sm, shv);
        float e1 = welem(tv.y, xv.y, gmin, m1, m2, sl, sm, shv);
        float e2 = welem(tv.z, xv.z, gmin, m1, m2, sl, sm, shv);
        float e3 = welem(tv.w, xv.w, gmin, m1, m2, sl, sm, shv);
        acc += (double)e0 + (double)e1 + (double)e2 + (double)e3;
    }
    if (tid == 0) {  // scalar tail
        for (int j = (n4 << 2); j < n; j++)
            acc += (double)welem(t[j], x[j], gmin, m1, m2, sl, sm, shv);
    }

    acc = wred_sum(acc);
    __shared__ double sh_s[NWAVES];
    int wid = threadIdx.x >> 6, lane = threadIdx.x & 63;
    if (lane == 0) sh_s[wid] = acc;
    __syncthreads();
    if (threadIdx.x == 0) {
        double S = sh_s[0];
        for (int k = 1; k < NWAVES; k++) S += sh_s[k];
        bsum[blockIdx.x] = S;
    }
}

// ---------- pass 4: final mean ----------
__global__ void __launch_bounds__(TBS) k_final(
        const double* __restrict__ bsum, long long n, float* __restrict__ out) {
    double s = 0.0;
    for (int i = threadIdx.x; i < NB; i += TBS) s += bsum[i];
    s = wred_sum(s);
    __shared__ double sh_s[TNW];
    int wid = threadIdx.x >> 6, lane = threadIdx.x & 63;
    if (lane == 0) sh_s[wid] = s;
    __syncthreads();
    if (threadIdx.x == 0) {
        double S = sh_s[0];
        for (int i = 1; i < TNW; i++) S += sh_s[i];
        out[0] = (float)(S / (double)n);
    }
}

extern "C" void kernel_launch(void* const* d_in, const int* in_sizes, int n_in,
                              void* d_out, int out_size, void* d_ws, size_t ws_size,
                              hipStream_t stream) {
    const float* inp = (const float*)d_in[0];
    const float* tgt = (const float*)d_in[1];
    int n = in_sizes[0];

    // workspace layout (bytes); plain stores -> no init needed:
    //   [0,      16384) double sum1[NB]
    //   [16384,  32768) double ss1[NB]
    //   [32768,  40960) float  mn1[NB]
    //   [40960,  49152) float  mx1[NB]
    //   [49152,  49216) float  stats[16]
    //   [49280,  65664) double sum2[NB]
    char* ws = (char*)d_ws;
    double* sum1  = (double*)(ws);
    double* ss1   = (double*)(ws + 16384);
    float*  mn1   = (float*)(ws + 32768);
    float*  mx1   = (float*)(ws + 40960);
    float*  stats = (float*)(ws + 49152);
    double* sum2  = (double*)(ws + 49280);

    k_stats<<<NB, BS, 0, stream>>>(tgt, n, sum1, ss1, mn1, mx1);
    k_finalize_stats<<<1, TBS, 0, stream>>>(sum1, ss1, mn1, mx1, (long long)n, stats);
    k_loss<<<NB, BS, 0, stream>>>(inp, tgt, n, stats, sum2);
    k_final<<<1, TBS, 0, stream>>>(sum2, (long long)n, (float*)d_out);
}